// Round 9
// baseline (654.105 us; speedup 1.0000x reference)
//
#include <hip/hip_runtime.h>

#define NG 8192
#define NC 4096
#define FG 512
#define FC 256
#define ALPHA 0.2f

typedef float f32x4 __attribute__((ext_vector_type(4)));
typedef short bf16x8 __attribute__((ext_vector_type(8)));

static __device__ __forceinline__ float leakyf(float x) { return fmaxf(x, ALPHA * x); }

static __device__ __forceinline__ unsigned short f2bf(float f) {
    unsigned u = __builtin_bit_cast(unsigned, f);
    u += 0x7fffu + ((u >> 16) & 1u);
    return (unsigned short)(u >> 16);
}

// pack two fp32 -> two bf16 (truncation) in ONE v_perm_b32
static __device__ __forceinline__ unsigned pack2bf(float lo, float hi) {
    return __builtin_amdgcn_perm(__builtin_bit_cast(unsigned, hi),
                                 __builtin_bit_cast(unsigned, lo), 0x07060302u);
}

static __device__ __forceinline__ float wred(float v) {
#pragma unroll
    for (int m = 1; m < 64; m <<= 1) v += __shfl_xor(v, m, 64);
    return v;
}

#define PACK_BLKS ((NG + NC + NG) / 4)
#define PROJ_BLKS (NG / 16 + NC / 16)

// ---------------- projection body: h = x@W [N,K]@[K,64] + bf16 h^T + 5 scalars
static __device__ __forceinline__ void proj_body(
    const float* __restrict__ x, const float* __restrict__ W, int K, int N,
    float* __restrict__ h, unsigned short* __restrict__ hT,
    const float* __restrict__ aA, const float* __restrict__ aB,
    const float* __restrict__ aC, const float* __restrict__ aD,
    const float* __restrict__ aG, const float* __restrict__ bG,
    float* __restrict__ sA, float* __restrict__ sB, float* __restrict__ sC,
    float* __restrict__ sD, float* __restrict__ gam, int blk)
{
    const int wave = threadIdx.x >> 6, lane = threadIdx.x & 63;
    const int r0 = blk * 16 + wave * 4;
    const float* xr = x + (size_t)r0 * K;
    float acc0 = 0.f, acc1 = 0.f, acc2 = 0.f, acc3 = 0.f;
    for (int k = 0; k < K; k += 4) {
        float4 x0 = *(const float4*)(xr + k);
        float4 x1 = *(const float4*)(xr + K + k);
        float4 x2 = *(const float4*)(xr + 2 * (size_t)K + k);
        float4 x3 = *(const float4*)(xr + 3 * (size_t)K + k);
        float w0 = W[(k + 0) * 64 + lane];
        float w1 = W[(k + 1) * 64 + lane];
        float w2 = W[(k + 2) * 64 + lane];
        float w3 = W[(k + 3) * 64 + lane];
        acc0 += x0.x * w0 + x0.y * w1 + x0.z * w2 + x0.w * w3;
        acc1 += x1.x * w0 + x1.y * w1 + x1.z * w2 + x1.w * w3;
        acc2 += x2.x * w0 + x2.y * w1 + x2.z * w2 + x2.w * w3;
        acc3 += x3.x * w0 + x3.y * w1 + x3.z * w2 + x3.w * w3;
    }
    float accs[4] = {acc0, acc1, acc2, acc3};
    unsigned short hb[4];
#pragma unroll
    for (int t = 0; t < 4; t++) {
        h[(size_t)(r0 + t) * 64 + lane] = accs[t];
        hb[t] = f2bf(accs[t]);                  // keep RNE for h itself
    }
    *(ushort4*)&hT[(size_t)lane * N + r0] = make_ushort4(hb[0], hb[1], hb[2], hb[3]);

    const float cA = aA[lane], cB = aB[lane], cC = aC[lane], cD = aD[lane], cG = aG[lane];
    const float bias = bG[0];
#pragma unroll
    for (int t = 0; t < 4; t++) {
        float vA = wred(accs[t] * cA);
        float vB = wred(accs[t] * cB);
        float vC = wred(accs[t] * cC);
        float vD = wred(accs[t] * cD);
        float vG = wred(accs[t] * cG);
        if (lane == 0) {
            sA[r0 + t] = vA; sB[r0 + t] = vB; sC[r0 + t] = vC; sD[r0 + t] = vD;
            gam[r0 + t] = 1.f / (1.f + __expf(-(vG + bias)));
        }
    }
}

// ---------------- ONE launch: bitmask packs (blocks [0,PACK)) + both projections
// Pack v2: 8 independent int4 loads per lane per iteration (128 B in flight
// per lane, 8 KB/wave — deep MLP) + ONE coalesced dword store of 32 mask bits.
__global__ __launch_bounds__(256) void prep_all(
    const int* __restrict__ gene_adj, const int* __restrict__ cell_adj,
    const int* __restrict__ gc_adj,
    unsigned char* __restrict__ bmGG, unsigned char* __restrict__ bmCC,
    unsigned char* __restrict__ bmGC,
    const float* __restrict__ gene_x, const float* __restrict__ W_g,
    const float* __restrict__ cell_x, const float* __restrict__ W_c,
    float* __restrict__ gene_h, unsigned short* __restrict__ gene_hT,
    float* __restrict__ cell_h, unsigned short* __restrict__ cell_hT,
    const float* __restrict__ a_gg, const float* __restrict__ a_gc,
    const float* __restrict__ a_cc, const float* __restrict__ a_cg,
    const float* __restrict__ Wgg, const float* __restrict__ bgg,
    const float* __restrict__ Wgc, const float* __restrict__ bgc,
    float* s1gg, float* s2gg, float* s1gc, float* s2cg, float* gamg,
    float* s1cc, float* s2cc, float* s2gc, float* s1cg, float* gamc)
{
    if (blockIdx.x < PACK_BLKS) {
        const int wave = threadIdx.x >> 6, lane = threadIdx.x & 63;
        const int r = blockIdx.x * 4 + wave;
        const int* row; unsigned* brow; int C;
        if (r < NG)           { row = gene_adj + (size_t)r * NG;              brow = (unsigned*)(bmGG + (size_t)r * (NG >> 3));              C = NG; }
        else if (r < NG + NC) { int rr = r - NG;      row = cell_adj + (size_t)rr * NC; brow = (unsigned*)(bmCC + (size_t)rr * (NC >> 3)); C = NC; }
        else                  { int rr = r - NG - NC; row = gc_adj   + (size_t)rr * NC; brow = (unsigned*)(bmGC + (size_t)rr * (NC >> 3)); C = NC; }
        for (int q = 0; q < C; q += 2048) {               // wave covers 2048 ints/iter
            const int* base = row + q + lane * 32;        // lane: 32 consecutive ints
            int4 a[8];
#pragma unroll
            for (int t = 0; t < 8; t++) a[t] = *(const int4*)(base + t * 4);
            unsigned w = 0;
#pragma unroll
            for (int t = 0; t < 8; t++) {
                w |= (unsigned)(a[t].x > 0) << (4 * t + 0);
                w |= (unsigned)(a[t].y > 0) << (4 * t + 1);
                w |= (unsigned)(a[t].z > 0) << (4 * t + 2);
                w |= (unsigned)(a[t].w > 0) << (4 * t + 3);
            }
            brow[(q >> 5) + lane] = w;                    // coalesced 256 B/wave
        }
    } else {
        int blk = blockIdx.x - PACK_BLKS;
        if (blk < NG / 16)
            proj_body(gene_x, W_g, FG, NG, gene_h, gene_hT,
                      a_gg, a_gg + 64, a_gc, a_cg + 64, Wgg, bgg,
                      s1gg, s2gg, s1gc, s2cg, gamg, blk);
        else
            proj_body(cell_x, W_c, FC, NC, cell_h, cell_hT,
                      a_cc, a_cc + 64, a_gc + 64, a_cg, Wgc, bgc,
                      s1cc, s2cc, s2gc, s1cg, gamc, blk - NG / 16);
    }
}

// ---------------- relation compute core on a staged 256-j chunk
// af = trunc-bf16(w); l via 5th MFMA against all-ones B; num via 4 MFMA.
static __device__ __forceinline__ void rel_chunk_compute(
    const unsigned short* hbuf, const float* s2buf,
    unsigned mask_words[8], float s1v, int m, int kp,
    f32x4& acc0, f32x4& acc1, f32x4& acc2, f32x4& acc3, f32x4& acc4,
    const bf16x8 bones)
{
#pragma unroll
    for (int g = 0; g < 8; ++g) {
        const int jl = g * 32 + kp * 8;
        float4 sa = *(const float4*)&s2buf[jl];
        float4 sb = *(const float4*)&s2buf[jl + 4];
        unsigned byte = (mask_words[g] >> (kp * 8)) & 0xffu;
        bf16x8 b0 = *(const bf16x8*)&hbuf[(0 * 16 + m) * 264 + jl];
        bf16x8 b1 = *(const bf16x8*)&hbuf[(1 * 16 + m) * 264 + jl];
        bf16x8 b2 = *(const bf16x8*)&hbuf[(2 * 16 + m) * 264 + jl];
        bf16x8 b3 = *(const bf16x8*)&hbuf[(3 * 16 + m) * 264 + jl];
        float s2v[8] = {sa.x, sa.y, sa.z, sa.w, sb.x, sb.y, sb.z, sb.w};
        float w[8];
#pragma unroll
        for (int t = 0; t < 8; t++) {
            float e = s1v + s2v[t];
            w[t] = ((byte >> t) & 1u) ? __expf(leakyf(e)) : 0.f;
        }
        uint4 pk = {pack2bf(w[0], w[1]), pack2bf(w[2], w[3]),
                    pack2bf(w[4], w[5]), pack2bf(w[6], w[7])};
        bf16x8 af = __builtin_bit_cast(bf16x8, pk);
        acc0 = __builtin_amdgcn_mfma_f32_16x16x32_bf16(af, b0, acc0, 0, 0, 0);
        acc1 = __builtin_amdgcn_mfma_f32_16x16x32_bf16(af, b1, acc1, 0, 0, 0);
        acc2 = __builtin_amdgcn_mfma_f32_16x16x32_bf16(af, b2, acc2, 0, 0, 0);
        acc3 = __builtin_amdgcn_mfma_f32_16x16x32_bf16(af, b3, acc3, 0, 0, 0);
        acc4 = __builtin_amdgcn_mfma_f32_16x16x32_bf16(af, bones, acc4, 0, 0, 0);
    }
}

static __device__ __forceinline__ void rel_epilogue(
    const f32x4& acc0, const f32x4& acc1, const f32x4& acc2, const f32x4& acc3,
    const f32x4& acc4, float* __restrict__ num, float* __restrict__ lsum,
    int Ns, int p, int strip, int wave, int m, int kp)
{
    const int orow0 = strip * 64 + wave * 16 + kp * 4;
#pragma unroll
    for (int r = 0; r < 4; r++) {
        size_t base = ((size_t)p * Ns + orow0 + r) * 64;
        num[base + m]      = acc0[r];
        num[base + 16 + m] = acc1[r];
        num[base + 32 + m] = acc2[r];
        num[base + 48 + m] = acc3[r];
        if (m == 0) lsum[(size_t)p * Ns + orow0 + r] = acc4[r];
    }
}

// row relation: mask from row-major bitmask (bits along j)
static __device__ __forceinline__ void rel_row_body(
    unsigned short* hbuf, float* s2buf,
    const unsigned char* __restrict__ bm, int bm_ld,
    const float* __restrict__ s1, const float* __restrict__ s2,
    const unsigned short* __restrict__ hT, int Nd,
    float* __restrict__ num, float* __restrict__ lsum, int Ns, int JS,
    int strip, int p)
{
    const int wave = threadIdx.x >> 6, lane = threadIdx.x & 63;
    const int m = lane & 15, kp = lane >> 4;
    const int jlen = Nd / JS, jbase = p * jlen;
    const int i_row = strip * 64 + wave * 16 + m;
    const float s1v = s1[i_row];
    const unsigned char* bmrow = bm + (size_t)i_row * bm_ld;
    bf16x8 bones;
#pragma unroll
    for (int t = 0; t < 8; t++) bones[t] = (short)0x3f80;
    f32x4 acc0 = {0.f, 0.f, 0.f, 0.f}, acc1 = acc0, acc2 = acc0, acc3 = acc0, acc4 = acc0;

    for (int jc = jbase; jc < jbase + jlen; jc += 256) {
        uint4 q0 = *(const uint4*)(bmrow + (jc >> 3));
        uint4 q1 = *(const uint4*)(bmrow + (jc >> 3) + 16);
        for (int idx = threadIdx.x; idx < 2048; idx += 256) {
            int c = idx >> 5, off = (idx & 31) * 8;
            *(int4*)&hbuf[c * 264 + off] = *(const int4*)&hT[(size_t)c * Nd + jc + off];
        }
        s2buf[threadIdx.x] = s2[jc + threadIdx.x];
        __syncthreads();
        unsigned words[8] = {q0.x, q0.y, q0.z, q0.w, q1.x, q1.y, q1.z, q1.w};
        rel_chunk_compute(hbuf, s2buf, words, s1v, m, kp, acc0, acc1, acc2, acc3, acc4, bones);
        __syncthreads();
    }
    rel_epilogue(acc0, acc1, acc2, acc3, acc4, num, lsum, Ns, p, strip, wave, m, kp);
}

// col relation (cg): mask bit [j][i] from row-major gc bitmask; bytes are
// near-broadcast across the wave (16 consecutive i -> 2 bytes, 1 line).
static __device__ __forceinline__ void rel_col_body(
    unsigned short* hbuf, float* s2buf,
    const unsigned char* __restrict__ bm, int bm_ld,
    const float* __restrict__ s1, const float* __restrict__ s2,
    const unsigned short* __restrict__ hT, int Nd,
    float* __restrict__ num, float* __restrict__ lsum, int Ns, int JS,
    int strip, int p)
{
    const int wave = threadIdx.x >> 6, lane = threadIdx.x & 63;
    const int m = lane & 15, kp = lane >> 4;
    const int jlen = Nd / JS, jbase = p * jlen;
    const int i_row = strip * 64 + wave * 16 + m;          // cell index
    const float s1v = s1[i_row];
    const int bcol = i_row >> 3, bbit = i_row & 7;
    bf16x8 bones;
#pragma unroll
    for (int t = 0; t < 8; t++) bones[t] = (short)0x3f80;
    f32x4 acc0 = {0.f, 0.f, 0.f, 0.f}, acc1 = acc0, acc2 = acc0, acc3 = acc0, acc4 = acc0;

    for (int jc = jbase; jc < jbase + jlen; jc += 256) {
        for (int idx = threadIdx.x; idx < 2048; idx += 256) {
            int c = idx >> 5, off = (idx & 31) * 8;
            *(int4*)&hbuf[c * 264 + off] = *(const int4*)&hT[(size_t)c * Nd + jc + off];
        }
        s2buf[threadIdx.x] = s2[jc + threadIdx.x];
        __syncthreads();
#pragma unroll
        for (int g = 0; g < 8; ++g) {
            const int jl = g * 32 + kp * 8;
            const int jg = jc + jl;
            const unsigned char* bp = bm + (size_t)jg * bm_ld + bcol;
            unsigned mw = 0;
#pragma unroll
            for (int t = 0; t < 8; t++)
                mw |= ((unsigned)((bp[(size_t)t * bm_ld] >> bbit) & 1u)) << t;
            float4 sa = *(const float4*)&s2buf[jl];
            float4 sb = *(const float4*)&s2buf[jl + 4];
            bf16x8 b0 = *(const bf16x8*)&hbuf[(0 * 16 + m) * 264 + jl];
            bf16x8 b1 = *(const bf16x8*)&hbuf[(1 * 16 + m) * 264 + jl];
            bf16x8 b2 = *(const bf16x8*)&hbuf[(2 * 16 + m) * 264 + jl];
            bf16x8 b3 = *(const bf16x8*)&hbuf[(3 * 16 + m) * 264 + jl];
            float s2v[8] = {sa.x, sa.y, sa.z, sa.w, sb.x, sb.y, sb.z, sb.w};
            float w[8];
#pragma unroll
            for (int t = 0; t < 8; t++) {
                float e = s1v + s2v[t];
                w[t] = ((mw >> t) & 1u) ? __expf(leakyf(e)) : 0.f;
            }
            uint4 pk = {pack2bf(w[0], w[1]), pack2bf(w[2], w[3]),
                        pack2bf(w[4], w[5]), pack2bf(w[6], w[7])};
            bf16x8 af = __builtin_bit_cast(bf16x8, pk);
            acc0 = __builtin_amdgcn_mfma_f32_16x16x32_bf16(af, b0, acc0, 0, 0, 0);
            acc1 = __builtin_amdgcn_mfma_f32_16x16x32_bf16(af, b1, acc1, 0, 0, 0);
            acc2 = __builtin_amdgcn_mfma_f32_16x16x32_bf16(af, b2, acc2, 0, 0, 0);
            acc3 = __builtin_amdgcn_mfma_f32_16x16x32_bf16(af, b3, acc3, 0, 0, 0);
            acc4 = __builtin_amdgcn_mfma_f32_16x16x32_bf16(af, bones, acc4, 0, 0, 0);
        }
        __syncthreads();
    }
    rel_epilogue(acc0, acc1, acc2, acc3, acc4, num, lsum, Ns, p, strip, wave, m, kp);
}

// ---------------- ALL four relations, ONE dispatch
// blocks: [0,1024) gg JS=8 | [1024,1536) cc JS=8 | [1536,2048) gc JS=4 | [2048,2560) cg JS=8
__global__ __launch_bounds__(256, 4) void rel_fused(
    const unsigned char* __restrict__ bmGG, const unsigned char* __restrict__ bmCC,
    const unsigned char* __restrict__ bmGC,
    const float* __restrict__ s1gg, const float* __restrict__ s2gg,
    const float* __restrict__ s1cc, const float* __restrict__ s2cc,
    const float* __restrict__ s1gc, const float* __restrict__ s2gc,
    const float* __restrict__ s1cg, const float* __restrict__ s2cg,
    const unsigned short* __restrict__ gene_hT, const unsigned short* __restrict__ cell_hT,
    float* __restrict__ numGG, float* __restrict__ lGG,
    float* __restrict__ numCC, float* __restrict__ lCC,
    float* __restrict__ numGC, float* __restrict__ lGC,
    float* __restrict__ numCG, float* __restrict__ lCG)
{
    __shared__ __align__(16) unsigned short hbuf[64 * 264];   // 33792 B
    __shared__ __align__(16) float s2buf[256];                // 1 KB -> 4 blocks/CU
    const int b = blockIdx.x;
    if (b < 1024) {
        const int w = b;
        rel_row_body(hbuf, s2buf, bmGG, NG / 8, s1gg, s2gg, gene_hT, NG,
                     numGG, lGG, NG, 8, w >> 3, w & 7);
    } else if (b < 1536) {
        const int w = b - 1024;
        rel_row_body(hbuf, s2buf, bmCC, NC / 8, s1cc, s2cc, cell_hT, NC,
                     numCC, lCC, NC, 8, w >> 3, w & 7);
    } else if (b < 2048) {
        const int w = b - 1536;
        rel_row_body(hbuf, s2buf, bmGC, NC / 8, s1gc, s2gc, cell_hT, NC,
                     numGC, lGC, NG, 4, w >> 2, w & 3);
    } else {
        const int w = b - 2048;
        rel_col_body(hbuf, s2buf, bmGC, NC / 8, s1cg, s2cg, gene_hT, NG,
                     numCG, lCG, NC, 8, w >> 3, w & 7);
    }
}

// ---------------- combine + epilogue (both outputs, one launch)
static __device__ __forceinline__ void combine_body(
    const float* __restrict__ numS, const float* __restrict__ lS, int JSS,
    const float* __restrict__ numX, const float* __restrict__ lX, int JSX,
    int Ns, const float* __restrict__ h, const float* __restrict__ gam,
    float* __restrict__ out, int blk)
{
    int idx = blk * 256 + threadIdx.x;
    int i = idx >> 6, c = idx & 63;
    float nS = 0.f, dS = 0.f, nX = 0.f, dX = 0.f;
    for (int p = 0; p < JSS; p++) {
        nS += numS[((size_t)p * Ns + i) * 64 + c];
        dS += lS[(size_t)p * Ns + i];
    }
    for (int p = 0; p < JSX; p++) {
        nX += numX[((size_t)p * Ns + i) * 64 + c];
        dX += lX[(size_t)p * Ns + i];
    }
    float v = h[idx] + nS / dS + gam[i] * (nX / dX);
    out[idx] = leakyf(v);
}

__global__ __launch_bounds__(256) void combine_all(
    const float* __restrict__ numGG, const float* __restrict__ lGG,
    const float* __restrict__ numGC, const float* __restrict__ lGC,
    const float* __restrict__ numCC, const float* __restrict__ lCC,
    const float* __restrict__ numCG, const float* __restrict__ lCG,
    const float* __restrict__ gene_h, const float* __restrict__ cell_h,
    const float* __restrict__ gamg, const float* __restrict__ gamc,
    float* __restrict__ out_gene, float* __restrict__ out_cell)
{
    if (blockIdx.x < NG * 64 / 256)
        combine_body(numGG, lGG, 8, numGC, lGC, 4, NG, gene_h, gamg, out_gene, blockIdx.x);
    else
        combine_body(numCC, lCC, 8, numCG, lCG, 8, NC, cell_h, gamc, out_cell,
                     blockIdx.x - NG * 64 / 256);
}

extern "C" void kernel_launch(void* const* d_in, const int* in_sizes, int n_in,
                              void* d_out, int out_size, void* d_ws, size_t ws_size,
                              hipStream_t stream)
{
    const float* gene_x = (const float*)d_in[0];
    const float* cell_x = (const float*)d_in[1];
    const float* W_g    = (const float*)d_in[2];
    const float* W_c    = (const float*)d_in[3];
    const float* a_gg   = (const float*)d_in[4];
    const float* a_gc   = (const float*)d_in[5];
    const float* a_cc   = (const float*)d_in[6];
    const float* a_cg   = (const float*)d_in[7];
    const float* Wgg    = (const float*)d_in[8];
    const float* bgg    = (const float*)d_in[9];
    const float* Wgc    = (const float*)d_in[10];
    const float* bgc    = (const float*)d_in[11];
    const int* gene_adj = (const int*)d_in[12];
    const int* cell_adj = (const int*)d_in[13];
    const int* gc_adj   = (const int*)d_in[14];

    size_t off = 0;
    char* wsb = (char*)d_ws;
    auto alloc = [&](size_t bytes) -> void* {
        void* p = wsb + off;
        off += (bytes + 255) & ~(size_t)255;
        return p;
    };
    const int JS_GG = 8, JS_CC = 8, JS_GC = 4, JS_CG = 8;

    float* gene_h = (float*)alloc((size_t)NG * 64 * 4);
    float* cell_h = (float*)alloc((size_t)NC * 64 * 4);
    unsigned short* gene_hT = (unsigned short*)alloc((size_t)NG * 64 * 2);
    unsigned short* cell_hT = (unsigned short*)alloc((size_t)NC * 64 * 2);
    unsigned char* bmGG = (unsigned char*)alloc((size_t)NG * (NG / 8));
    unsigned char* bmCC = (unsigned char*)alloc((size_t)NC * (NC / 8));
    unsigned char* bmGC = (unsigned char*)alloc((size_t)NG * (NC / 8));
    float* s1gg = (float*)alloc(NG * 4);
    float* s2gg = (float*)alloc(NG * 4);
    float* s1gc = (float*)alloc(NG * 4);
    float* s2cg = (float*)alloc(NG * 4);
    float* gamg = (float*)alloc(NG * 4);
    float* s1cc = (float*)alloc(NC * 4);
    float* s2cc = (float*)alloc(NC * 4);
    float* s2gc = (float*)alloc(NC * 4);
    float* s1cg = (float*)alloc(NC * 4);
    float* gamc = (float*)alloc(NC * 4);
    float* numGG = (float*)alloc((size_t)NG * 64 * JS_GG * 4);
    float* lGG   = (float*)alloc((size_t)NG * JS_GG * 4);
    float* numGC = (float*)alloc((size_t)NG * 64 * JS_GC * 4);
    float* lGC   = (float*)alloc((size_t)NG * JS_GC * 4);
    float* numCC = (float*)alloc((size_t)NC * 64 * JS_CC * 4);
    float* lCC   = (float*)alloc((size_t)NC * JS_CC * 4);
    float* numCG = (float*)alloc((size_t)NC * 64 * JS_CG * 4);
    float* lCG   = (float*)alloc((size_t)NC * JS_CG * 4);

    float* out_gene = (float*)d_out;
    float* out_cell = (float*)d_out + (size_t)NG * 64;

    // 3 launches total
    prep_all<<<PACK_BLKS + PROJ_BLKS, 256, 0, stream>>>(
        gene_adj, cell_adj, gc_adj, bmGG, bmCC, bmGC,
        gene_x, W_g, cell_x, W_c, gene_h, gene_hT, cell_h, cell_hT,
        a_gg, a_gc, a_cc, a_cg, Wgg, bgg, Wgc, bgc,
        s1gg, s2gg, s1gc, s2cg, gamg, s1cc, s2cc, s2gc, s1cg, gamc);

    rel_fused<<<2560, 256, 0, stream>>>(bmGG, bmCC, bmGC,
        s1gg, s2gg, s1cc, s2cc, s1gc, s2gc, s1cg, s2cg,
        gene_hT, cell_hT,
        numGG, lGG, numCC, lCC, numGC, lGC, numCG, lCG);

    combine_all<<<(NG + NC) * 64 / 256, 256, 0, stream>>>(
        numGG, lGG, numGC, lGC, numCC, lCC, numCG, lCG,
        gene_h, cell_h, gamg, gamc, out_gene, out_cell);
}

// Round 10
// 632.865 us; speedup vs baseline: 1.0336x; 1.0336x over previous
//
#include <hip/hip_runtime.h>

#define NG 8192
#define NC 4096
#define FG 512
#define FC 256
#define ALPHA 0.2f

typedef float f32x4 __attribute__((ext_vector_type(4)));
typedef short bf16x8 __attribute__((ext_vector_type(8)));

static __device__ __forceinline__ float leakyf(float x) { return fmaxf(x, ALPHA * x); }

static __device__ __forceinline__ unsigned short f2bf(float f) {
    unsigned u = __builtin_bit_cast(unsigned, f);
    u += 0x7fffu + ((u >> 16) & 1u);
    return (unsigned short)(u >> 16);
}

// pack two fp32 -> two bf16 (truncation) in ONE v_perm_b32
static __device__ __forceinline__ unsigned pack2bf(float lo, float hi) {
    return __builtin_amdgcn_perm(__builtin_bit_cast(unsigned, hi),
                                 __builtin_bit_cast(unsigned, lo), 0x07060302u);
}

static __device__ __forceinline__ float wred(float v) {
#pragma unroll
    for (int m = 1; m < 64; m <<= 1) v += __shfl_xor(v, m, 64);
    return v;
}

// ---------------- bitmask pack (standalone — R6-proven <158 us). Segment order:
// gc first (restored last -> L3-hottest), then cell, then gene (cold anyway).
__global__ __launch_bounds__(256) void pack_all(
    const int* __restrict__ gene_adj, const int* __restrict__ cell_adj,
    const int* __restrict__ gc_adj,
    unsigned char* __restrict__ bmGG, unsigned char* __restrict__ bmCC,
    unsigned char* __restrict__ bmGC)
{
    const int wave = threadIdx.x >> 6, lane = threadIdx.x & 63;
    const int r = blockIdx.x * 4 + wave;
    const int* row; unsigned char* brow; int C;
    if (r < NG)           { row = gc_adj   + (size_t)r * NC;              brow = bmGC + (size_t)r * (NC >> 3);              C = NC; }
    else if (r < NG + NC) { int rr = r - NG;      row = cell_adj + (size_t)rr * NC; brow = bmCC + (size_t)rr * (NC >> 3); C = NC; }
    else                  { int rr = r - NG - NC; row = gene_adj + (size_t)rr * NG; brow = bmGG + (size_t)rr * (NG >> 3); C = NG; }
    for (int j = lane * 8; j < C; j += 512) {
        int4 a0 = *(const int4*)(row + j);
        int4 a1 = *(const int4*)(row + j + 4);
        unsigned b = (unsigned)(a0.x > 0)        | ((unsigned)(a0.y > 0) << 1)
                   | ((unsigned)(a0.z > 0) << 2) | ((unsigned)(a0.w > 0) << 3)
                   | ((unsigned)(a1.x > 0) << 4) | ((unsigned)(a1.y > 0) << 5)
                   | ((unsigned)(a1.z > 0) << 6) | ((unsigned)(a1.w > 0) << 7);
        brow[j >> 3] = (unsigned char)b;
    }
}

// ---------------- projection body: h = x@W [N,K]@[K,64] + bf16 h^T + 5 scalars
static __device__ __forceinline__ void proj_body(
    const float* __restrict__ x, const float* __restrict__ W, int K, int N,
    float* __restrict__ h, unsigned short* __restrict__ hT,
    const float* __restrict__ aA, const float* __restrict__ aB,
    const float* __restrict__ aC, const float* __restrict__ aD,
    const float* __restrict__ aG, const float* __restrict__ bG,
    float* __restrict__ sA, float* __restrict__ sB, float* __restrict__ sC,
    float* __restrict__ sD, float* __restrict__ gam, int blk)
{
    const int wave = threadIdx.x >> 6, lane = threadIdx.x & 63;
    const int r0 = blk * 16 + wave * 4;
    const float* xr = x + (size_t)r0 * K;
    float acc0 = 0.f, acc1 = 0.f, acc2 = 0.f, acc3 = 0.f;
    for (int k = 0; k < K; k += 4) {
        float4 x0 = *(const float4*)(xr + k);
        float4 x1 = *(const float4*)(xr + K + k);
        float4 x2 = *(const float4*)(xr + 2 * (size_t)K + k);
        float4 x3 = *(const float4*)(xr + 3 * (size_t)K + k);
        float w0 = W[(k + 0) * 64 + lane];
        float w1 = W[(k + 1) * 64 + lane];
        float w2 = W[(k + 2) * 64 + lane];
        float w3 = W[(k + 3) * 64 + lane];
        acc0 += x0.x * w0 + x0.y * w1 + x0.z * w2 + x0.w * w3;
        acc1 += x1.x * w0 + x1.y * w1 + x1.z * w2 + x1.w * w3;
        acc2 += x2.x * w0 + x2.y * w1 + x2.z * w2 + x2.w * w3;
        acc3 += x3.x * w0 + x3.y * w1 + x3.z * w2 + x3.w * w3;
    }
    float accs[4] = {acc0, acc1, acc2, acc3};
    unsigned short hb[4];
#pragma unroll
    for (int t = 0; t < 4; t++) {
        h[(size_t)(r0 + t) * 64 + lane] = accs[t];
        hb[t] = f2bf(accs[t]);
    }
    *(ushort4*)&hT[(size_t)lane * N + r0] = make_ushort4(hb[0], hb[1], hb[2], hb[3]);

    const float cA = aA[lane], cB = aB[lane], cC = aC[lane], cD = aD[lane], cG = aG[lane];
    const float bias = bG[0];
#pragma unroll
    for (int t = 0; t < 4; t++) {
        float vA = wred(accs[t] * cA);
        float vB = wred(accs[t] * cB);
        float vC = wred(accs[t] * cC);
        float vD = wred(accs[t] * cD);
        float vG = wred(accs[t] * cG);
        if (lane == 0) {
            sA[r0 + t] = vA; sB[r0 + t] = vB; sC[r0 + t] = vC; sD[r0 + t] = vD;
            gam[r0 + t] = 1.f / (1.f + __expf(-(vG + bias)));
        }
    }
}

// standalone (R6-proven): one launch for both projections
__global__ __launch_bounds__(256) void proj_all(
    const float* __restrict__ gene_x, const float* __restrict__ W_g,
    const float* __restrict__ cell_x, const float* __restrict__ W_c,
    float* __restrict__ gene_h, unsigned short* __restrict__ gene_hT,
    float* __restrict__ cell_h, unsigned short* __restrict__ cell_hT,
    const float* __restrict__ a_gg, const float* __restrict__ a_gc,
    const float* __restrict__ a_cc, const float* __restrict__ a_cg,
    const float* __restrict__ Wgg, const float* __restrict__ bgg,
    const float* __restrict__ Wgc, const float* __restrict__ bgc,
    float* s1gg, float* s2gg, float* s1gc, float* s2cg, float* gamg,
    float* s1cc, float* s2cc, float* s2gc, float* s1cg, float* gamc)
{
    if (blockIdx.x < NG / 16)
        proj_body(gene_x, W_g, FG, NG, gene_h, gene_hT,
                  a_gg, a_gg + 64, a_gc, a_cg + 64, Wgg, bgg,
                  s1gg, s2gg, s1gc, s2cg, gamg, blockIdx.x);
    else
        proj_body(cell_x, W_c, FC, NC, cell_h, cell_hT,
                  a_cc, a_cc + 64, a_gc + 64, a_cg, Wgc, bgc,
                  s1cc, s2cc, s2gc, s1cg, gamc, blockIdx.x - NG / 16);
}

// ---------------- rel epilogue (shared)
static __device__ __forceinline__ void rel_epilogue(
    const f32x4& acc0, const f32x4& acc1, const f32x4& acc2, const f32x4& acc3,
    const f32x4& acc4, float* __restrict__ num, float* __restrict__ lsum,
    int Ns, int p, int strip, int wave, int m, int kp)
{
    const int orow0 = strip * 64 + wave * 16 + kp * 4;
#pragma unroll
    for (int r = 0; r < 4; r++) {
        size_t base = ((size_t)p * Ns + orow0 + r) * 64;
        num[base + m]      = acc0[r];
        num[base + 16 + m] = acc1[r];
        num[base + 32 + m] = acc2[r];
        num[base + 48 + m] = acc3[r];
        if (m == 0) lsum[(size_t)p * Ns + orow0 + r] = acc4[r];
    }
}

// row relation, 128-j chunks (half the barrier quantum of R8, 6 blocks/CU)
static __device__ __forceinline__ void rel_row_body(
    unsigned short* hbuf, float* s2buf,
    const unsigned char* __restrict__ bm, int bm_ld,
    const float* __restrict__ s1, const float* __restrict__ s2,
    const unsigned short* __restrict__ hT, int Nd,
    float* __restrict__ num, float* __restrict__ lsum, int Ns, int JS,
    int strip, int p)
{
    const int wave = threadIdx.x >> 6, lane = threadIdx.x & 63;
    const int m = lane & 15, kp = lane >> 4;
    const int jlen = Nd / JS, jbase = p * jlen;
    const int i_row = strip * 64 + wave * 16 + m;
    const float s1v = s1[i_row];
    const unsigned char* bmrow = bm + (size_t)i_row * bm_ld;
    bf16x8 bones;
#pragma unroll
    for (int t = 0; t < 8; t++) bones[t] = (short)0x3f80;
    f32x4 acc0 = {0.f, 0.f, 0.f, 0.f}, acc1 = acc0, acc2 = acc0, acc3 = acc0, acc4 = acc0;

    for (int jc = jbase; jc < jbase + jlen; jc += 128) {
        uint4 q = *(const uint4*)(bmrow + (jc >> 3));       // 128 mask bits
        for (int idx = threadIdx.x; idx < 1024; idx += 256) {
            int c = idx >> 4, off = (idx & 15) * 8;
            *(int4*)&hbuf[c * 136 + off] = *(const int4*)&hT[(size_t)c * Nd + jc + off];
        }
        if (threadIdx.x < 128) s2buf[threadIdx.x] = s2[jc + threadIdx.x];
        __syncthreads();
        unsigned words[4] = {q.x, q.y, q.z, q.w};
#pragma unroll
        for (int g = 0; g < 4; ++g) {
            const int jl = g * 32 + kp * 8;
            float4 sa = *(const float4*)&s2buf[jl];
            float4 sb = *(const float4*)&s2buf[jl + 4];
            unsigned byte = (words[g] >> (kp * 8)) & 0xffu;
            bf16x8 b0 = *(const bf16x8*)&hbuf[(0 * 16 + m) * 136 + jl];
            bf16x8 b1 = *(const bf16x8*)&hbuf[(1 * 16 + m) * 136 + jl];
            bf16x8 b2 = *(const bf16x8*)&hbuf[(2 * 16 + m) * 136 + jl];
            bf16x8 b3 = *(const bf16x8*)&hbuf[(3 * 16 + m) * 136 + jl];
            float s2v[8] = {sa.x, sa.y, sa.z, sa.w, sb.x, sb.y, sb.z, sb.w};
            float w[8];
#pragma unroll
            for (int t = 0; t < 8; t++) {
                float e = s1v + s2v[t];
                w[t] = ((byte >> t) & 1u) ? __expf(leakyf(e)) : 0.f;
            }
            uint4 pk = {pack2bf(w[0], w[1]), pack2bf(w[2], w[3]),
                        pack2bf(w[4], w[5]), pack2bf(w[6], w[7])};
            bf16x8 af = __builtin_bit_cast(bf16x8, pk);
            acc0 = __builtin_amdgcn_mfma_f32_16x16x32_bf16(af, b0, acc0, 0, 0, 0);
            acc1 = __builtin_amdgcn_mfma_f32_16x16x32_bf16(af, b1, acc1, 0, 0, 0);
            acc2 = __builtin_amdgcn_mfma_f32_16x16x32_bf16(af, b2, acc2, 0, 0, 0);
            acc3 = __builtin_amdgcn_mfma_f32_16x16x32_bf16(af, b3, acc3, 0, 0, 0);
            acc4 = __builtin_amdgcn_mfma_f32_16x16x32_bf16(af, bones, acc4, 0, 0, 0);
        }
        __syncthreads();
    }
    rel_epilogue(acc0, acc1, acc2, acc3, acc4, num, lsum, Ns, p, strip, wave, m, kp);
}

// col relation (cg), 128-j chunks: mask bit [j][i] from row-major gc bitmask
static __device__ __forceinline__ void rel_col_body(
    unsigned short* hbuf, float* s2buf,
    const unsigned char* __restrict__ bm, int bm_ld,
    const float* __restrict__ s1, const float* __restrict__ s2,
    const unsigned short* __restrict__ hT, int Nd,
    float* __restrict__ num, float* __restrict__ lsum, int Ns, int JS,
    int strip, int p)
{
    const int wave = threadIdx.x >> 6, lane = threadIdx.x & 63;
    const int m = lane & 15, kp = lane >> 4;
    const int jlen = Nd / JS, jbase = p * jlen;
    const int i_row = strip * 64 + wave * 16 + m;          // cell index
    const float s1v = s1[i_row];
    const int bcol = i_row >> 3, bbit = i_row & 7;
    bf16x8 bones;
#pragma unroll
    for (int t = 0; t < 8; t++) bones[t] = (short)0x3f80;
    f32x4 acc0 = {0.f, 0.f, 0.f, 0.f}, acc1 = acc0, acc2 = acc0, acc3 = acc0, acc4 = acc0;

    for (int jc = jbase; jc < jbase + jlen; jc += 128) {
        for (int idx = threadIdx.x; idx < 1024; idx += 256) {
            int c = idx >> 4, off = (idx & 15) * 8;
            *(int4*)&hbuf[c * 136 + off] = *(const int4*)&hT[(size_t)c * Nd + jc + off];
        }
        if (threadIdx.x < 128) s2buf[threadIdx.x] = s2[jc + threadIdx.x];
        __syncthreads();
#pragma unroll
        for (int g = 0; g < 4; ++g) {
            const int jl = g * 32 + kp * 8;
            const int jg = jc + jl;
            const unsigned char* bp = bm + (size_t)jg * bm_ld + bcol;
            unsigned mw = 0;
#pragma unroll
            for (int t = 0; t < 8; t++)
                mw |= ((unsigned)((bp[(size_t)t * bm_ld] >> bbit) & 1u)) << t;
            float4 sa = *(const float4*)&s2buf[jl];
            float4 sb = *(const float4*)&s2buf[jl + 4];
            bf16x8 b0 = *(const bf16x8*)&hbuf[(0 * 16 + m) * 136 + jl];
            bf16x8 b1 = *(const bf16x8*)&hbuf[(1 * 16 + m) * 136 + jl];
            bf16x8 b2 = *(const bf16x8*)&hbuf[(2 * 16 + m) * 136 + jl];
            bf16x8 b3 = *(const bf16x8*)&hbuf[(3 * 16 + m) * 136 + jl];
            float s2v[8] = {sa.x, sa.y, sa.z, sa.w, sb.x, sb.y, sb.z, sb.w};
            float w[8];
#pragma unroll
            for (int t = 0; t < 8; t++) {
                float e = s1v + s2v[t];
                w[t] = ((mw >> t) & 1u) ? __expf(leakyf(e)) : 0.f;
            }
            uint4 pk = {pack2bf(w[0], w[1]), pack2bf(w[2], w[3]),
                        pack2bf(w[4], w[5]), pack2bf(w[6], w[7])};
            bf16x8 af = __builtin_bit_cast(bf16x8, pk);
            acc0 = __builtin_amdgcn_mfma_f32_16x16x32_bf16(af, b0, acc0, 0, 0, 0);
            acc1 = __builtin_amdgcn_mfma_f32_16x16x32_bf16(af, b1, acc1, 0, 0, 0);
            acc2 = __builtin_amdgcn_mfma_f32_16x16x32_bf16(af, b2, acc2, 0, 0, 0);
            acc3 = __builtin_amdgcn_mfma_f32_16x16x32_bf16(af, b3, acc3, 0, 0, 0);
            acc4 = __builtin_amdgcn_mfma_f32_16x16x32_bf16(af, bones, acc4, 0, 0, 0);
        }
        __syncthreads();
    }
    rel_epilogue(acc0, acc1, acc2, acc3, acc4, num, lsum, Ns, p, strip, wave, m, kp);
}

// ---------------- ALL four relations, ONE dispatch, 18.4 KB LDS -> 6+ blocks/CU
// blocks: [0,1024) gg JS=8 | [1024,1536) cc JS=8 | [1536,2048) gc JS=4 | [2048,2560) cg JS=8
__global__ __launch_bounds__(256, 6) void rel_fused(
    const unsigned char* __restrict__ bmGG, const unsigned char* __restrict__ bmCC,
    const unsigned char* __restrict__ bmGC,
    const float* __restrict__ s1gg, const float* __restrict__ s2gg,
    const float* __restrict__ s1cc, const float* __restrict__ s2cc,
    const float* __restrict__ s1gc, const float* __restrict__ s2gc,
    const float* __restrict__ s1cg, const float* __restrict__ s2cg,
    const unsigned short* __restrict__ gene_hT, const unsigned short* __restrict__ cell_hT,
    float* __restrict__ numGG, float* __restrict__ lGG,
    float* __restrict__ numCC, float* __restrict__ lCC,
    float* __restrict__ numGC, float* __restrict__ lGC,
    float* __restrict__ numCG, float* __restrict__ lCG)
{
    __shared__ __align__(16) unsigned short hbuf[64 * 136];   // 17408 B
    __shared__ __align__(16) float s2buf[128];                // 512 B
    const int b = blockIdx.x;
    if (b < 1024) {
        const int w = b;
        rel_row_body(hbuf, s2buf, bmGG, NG / 8, s1gg, s2gg, gene_hT, NG,
                     numGG, lGG, NG, 8, w >> 3, w & 7);
    } else if (b < 1536) {
        const int w = b - 1024;
        rel_row_body(hbuf, s2buf, bmCC, NC / 8, s1cc, s2cc, cell_hT, NC,
                     numCC, lCC, NC, 8, w >> 3, w & 7);
    } else if (b < 2048) {
        const int w = b - 1536;
        rel_row_body(hbuf, s2buf, bmGC, NC / 8, s1gc, s2gc, cell_hT, NC,
                     numGC, lGC, NG, 4, w >> 2, w & 3);
    } else {
        const int w = b - 2048;
        rel_col_body(hbuf, s2buf, bmGC, NC / 8, s1cg, s2cg, gene_hT, NG,
                     numCG, lCG, NC, 8, w >> 3, w & 7);
    }
}

// ---------------- combine + epilogue (both outputs, one launch)
static __device__ __forceinline__ void combine_body(
    const float* __restrict__ numS, const float* __restrict__ lS, int JSS,
    const float* __restrict__ numX, const float* __restrict__ lX, int JSX,
    int Ns, const float* __restrict__ h, const float* __restrict__ gam,
    float* __restrict__ out, int blk)
{
    int idx = blk * 256 + threadIdx.x;
    int i = idx >> 6, c = idx & 63;
    float nS = 0.f, dS = 0.f, nX = 0.f, dX = 0.f;
    for (int p = 0; p < JSS; p++) {
        nS += numS[((size_t)p * Ns + i) * 64 + c];
        dS += lS[(size_t)p * Ns + i];
    }
    for (int p = 0; p < JSX; p++) {
        nX += numX[((size_t)p * Ns + i) * 64 + c];
        dX += lX[(size_t)p * Ns + i];
    }
    float v = h[idx] + nS / dS + gam[i] * (nX / dX);
    out[idx] = leakyf(v);
}

__global__ __launch_bounds__(256) void combine_all(
    const float* __restrict__ numGG, const float* __restrict__ lGG,
    const float* __restrict__ numGC, const float* __restrict__ lGC,
    const float* __restrict__ numCC, const float* __restrict__ lCC,
    const float* __restrict__ numCG, const float* __restrict__ lCG,
    const float* __restrict__ gene_h, const float* __restrict__ cell_h,
    const float* __restrict__ gamg, const float* __restrict__ gamc,
    float* __restrict__ out_gene, float* __restrict__ out_cell)
{
    if (blockIdx.x < NG * 64 / 256)
        combine_body(numGG, lGG, 8, numGC, lGC, 4, NG, gene_h, gamg, out_gene, blockIdx.x);
    else
        combine_body(numCC, lCC, 8, numCG, lCG, 8, NC, cell_h, gamc, out_cell,
                     blockIdx.x - NG * 64 / 256);
}

extern "C" void kernel_launch(void* const* d_in, const int* in_sizes, int n_in,
                              void* d_out, int out_size, void* d_ws, size_t ws_size,
                              hipStream_t stream)
{
    const float* gene_x = (const float*)d_in[0];
    const float* cell_x = (const float*)d_in[1];
    const float* W_g    = (const float*)d_in[2];
    const float* W_c    = (const float*)d_in[3];
    const float* a_gg   = (const float*)d_in[4];
    const float* a_gc   = (const float*)d_in[5];
    const float* a_cc   = (const float*)d_in[6];
    const float* a_cg   = (const float*)d_in[7];
    const float* Wgg    = (const float*)d_in[8];
    const float* bgg    = (const float*)d_in[9];
    const float* Wgc    = (const float*)d_in[10];
    const float* bgc    = (const float*)d_in[11];
    const int* gene_adj = (const int*)d_in[12];
    const int* cell_adj = (const int*)d_in[13];
    const int* gc_adj   = (const int*)d_in[14];

    size_t off = 0;
    char* wsb = (char*)d_ws;
    auto alloc = [&](size_t bytes) -> void* {
        void* p = wsb + off;
        off += (bytes + 255) & ~(size_t)255;
        return p;
    };
    const int JS_GG = 8, JS_CC = 8, JS_GC = 4, JS_CG = 8;

    float* gene_h = (float*)alloc((size_t)NG * 64 * 4);
    float* cell_h = (float*)alloc((size_t)NC * 64 * 4);
    unsigned short* gene_hT = (unsigned short*)alloc((size_t)NG * 64 * 2);
    unsigned short* cell_hT = (unsigned short*)alloc((size_t)NC * 64 * 2);
    unsigned char* bmGG = (unsigned char*)alloc((size_t)NG * (NG / 8));
    unsigned char* bmCC = (unsigned char*)alloc((size_t)NC * (NC / 8));
    unsigned char* bmGC = (unsigned char*)alloc((size_t)NG * (NC / 8));
    float* s1gg = (float*)alloc(NG * 4);
    float* s2gg = (float*)alloc(NG * 4);
    float* s1gc = (float*)alloc(NG * 4);
    float* s2cg = (float*)alloc(NG * 4);
    float* gamg = (float*)alloc(NG * 4);
    float* s1cc = (float*)alloc(NC * 4);
    float* s2cc = (float*)alloc(NC * 4);
    float* s2gc = (float*)alloc(NC * 4);
    float* s1cg = (float*)alloc(NC * 4);
    float* gamc = (float*)alloc(NC * 4);
    float* numGG = (float*)alloc((size_t)NG * 64 * JS_GG * 4);
    float* lGG   = (float*)alloc((size_t)NG * JS_GG * 4);
    float* numGC = (float*)alloc((size_t)NG * 64 * JS_GC * 4);
    float* lGC   = (float*)alloc((size_t)NG * JS_GC * 4);
    float* numCC = (float*)alloc((size_t)NC * 64 * JS_CC * 4);
    float* lCC   = (float*)alloc((size_t)NC * JS_CC * 4);
    float* numCG = (float*)alloc((size_t)NC * 64 * JS_CG * 4);
    float* lCG   = (float*)alloc((size_t)NC * JS_CG * 4);

    float* out_gene = (float*)d_out;
    float* out_cell = (float*)d_out + (size_t)NG * 64;

    // 4 launches
    pack_all<<<(NG + NC + NG) / 4, 256, 0, stream>>>(gene_adj, cell_adj, gc_adj,
        bmGG, bmCC, bmGC);

    proj_all<<<NG / 16 + NC / 16, 256, 0, stream>>>(
        gene_x, W_g, cell_x, W_c, gene_h, gene_hT, cell_h, cell_hT,
        a_gg, a_gc, a_cc, a_cg, Wgg, bgg, Wgc, bgc,
        s1gg, s2gg, s1gc, s2cg, gamg, s1cc, s2cc, s2gc, s1cg, gamc);

    rel_fused<<<2560, 256, 0, stream>>>(bmGG, bmCC, bmGC,
        s1gg, s2gg, s1cc, s2cc, s1gc, s2gc, s1cg, s2cg,
        gene_hT, cell_hT,
        numGG, lGG, numCC, lCC, numGC, lGC, numCG, lCG);

    combine_all<<<(NG + NC) * 64 / 256, 256, 0, stream>>>(
        numGG, lGG, numGC, lGC, numCC, lCC, numCG, lCG,
        gene_h, cell_h, gamg, gamc, out_gene, out_cell);
}